// Round 1
// baseline (2257.718 us; speedup 1.0000x reference)
//
#include <hip/hip_runtime.h>

// LSTM feedback net: B=16384, T=48 warmup, F=4, UNITS=256, 24 AR steps.
// Strategy: batch rows independent -> each block owns 64 rows for all 71 cell
// steps. h (bf16) in LDS, c (fp32) in VGPRs. z = hext @ Whext via MFMA
// 16x16x32 bf16 with K extended to 288 (rows 256..259 hold Wx, x_t lives in
// hext[256:260]); bias b initializes the accumulator. Wave w owns units
// [32w,32w+32) across all 4 gates so gate fusion is register-local.

typedef unsigned short u16;
typedef __attribute__((ext_vector_type(8))) short bf16x8;
typedef __attribute__((ext_vector_type(4))) float f32x4;

#define PITCH 296   // hext row pitch in elems (288 + 8 pad; 592B = 16*37, 2-way-bank only)
#define WARM 48
#define STEPS 71    // 48 warmup + 23 AR cell steps

__device__ __forceinline__ u16 f2bf(float f) {
    unsigned u = __float_as_uint(f);
    u += 0x7FFFu + ((u >> 16) & 1u);   // round-to-nearest-even
    return (u16)(u >> 16);
}

__device__ __forceinline__ float sigm(float x) {
    return __builtin_amdgcn_rcpf(1.0f + __expf(-x));
}
// tanh(x) = 2*sigmoid(2x)-1 ; saturates correctly at +/-inf without NaN
__device__ __forceinline__ float tanh_f(float x) {
    return __builtin_amdgcn_rcpf(1.0f + __expf(-2.0f * x)) * 2.0f - 1.0f;
}

// ---- prep: pack Whext (K=288 x N=1024) and Wd (K=256 x N=16 padded) into
// bf16 MFMA B-fragment blocks: block (kt, nt) = 64 lanes x 16B, lane l holds
// B[k0 + (l>>4)*8 + j][nt*16 + (l&15)], j=0..7.
__global__ void prep_weights(const float* __restrict__ Wx,
                             const float* __restrict__ Wh,
                             const float* __restrict__ Wd,
                             u16* __restrict__ whext,
                             u16* __restrict__ wdp) {
    int idx = blockIdx.x * 256 + threadIdx.x;   // one thread per 16B chunk
    if (idx < 36864) {                          // 9 kt * 64 nt * 64 lanes
        int lane = idx & 63;
        int blk = idx >> 6;
        int nt = blk & 63;
        int kt = blk >> 6;
        int kbase = kt * 32 + (lane >> 4) * 8;
        int n = nt * 16 + (lane & 15);
        u16 v[8];
#pragma unroll
        for (int j = 0; j < 8; ++j) {
            int k = kbase + j;
            float f = 0.0f;
            if (k < 256) f = Wh[k * 1024 + n];
            else if (k < 260) f = Wx[(k - 256) * 1024 + n];
            v[j] = f2bf(f);
        }
        ushort4* dst = (ushort4*)(whext + (size_t)idx * 8);
        dst[0] = make_ushort4(v[0], v[1], v[2], v[3]);
        dst[1] = make_ushort4(v[4], v[5], v[6], v[7]);
    } else if (idx < 36864 + 512) {             // Wd: 8 kt * 64 lanes, N-tile 0 only
        int id2 = idx - 36864;
        int lane = id2 & 63;
        int kt = id2 >> 6;
        int kbase = kt * 32 + (lane >> 4) * 8;
        int n = lane & 15;
        u16 v[8];
#pragma unroll
        for (int j = 0; j < 8; ++j) {
            int k = kbase + j;
            v[j] = (n < 4) ? f2bf(Wd[k * 4 + n]) : (u16)0;
        }
        ushort4* dst = (ushort4*)(wdp + (size_t)id2 * 8);
        dst[0] = make_ushort4(v[0], v[1], v[2], v[3]);
        dst[1] = make_ushort4(v[4], v[5], v[6], v[7]);
    }
}

__global__ __launch_bounds__(512, 2) void lstm_main(
    const float* __restrict__ x, const float* __restrict__ b,
    const float* __restrict__ bd, const u16* __restrict__ whext,
    const u16* __restrict__ wdp, float* __restrict__ out) {
    __shared__ u16 hbuf[64 * PITCH];   // hext: [row 0..63][k 0..287], bf16

    const int tid = threadIdx.x;
    const int w = tid >> 6;        // wave 0..7
    const int l = tid & 63;
    const int col = l & 15;
    const int quad = l >> 4;
    const long long rowBase = (long long)blockIdx.x * 64;

    for (int i = tid; i < 64 * PITCH; i += 512) hbuf[i] = 0;

    // bias regs + per-wave B-fragment indices (wave w -> units 32w..32w+31,
    // n-tiles {16g + 2w + hf})
    float bias[8];
    int nb[8];   // fragment index base: ntile*64 + lane
#pragma unroll
    for (int g = 0; g < 4; ++g)
#pragma unroll
        for (int hf = 0; hf < 2; ++hf) {
            int ntl = g * 2 + hf;
            int ntile = 16 * g + 2 * w + hf;
            bias[ntl] = b[ntile * 16 + col];
            nb[ntl] = ntile * 64 + l;
        }
    float bdv = (col < 4) ? bd[col] : 0.0f;

    __syncthreads();   // zero-fill complete before x_t(0) write

    if (w == 0) {      // x_t for step 0 -> hext[m][256:260]
        const float4 xv = *(const float4*)(x + (rowBase + l) * 192);
        u16* p = &hbuf[l * PITCH + 256];
        p[0] = f2bf(xv.x); p[1] = f2bf(xv.y); p[2] = f2bf(xv.z); p[3] = f2bf(xv.w);
    }

    f32x4 c[4][2];
#pragma unroll
    for (int mt = 0; mt < 4; ++mt)
#pragma unroll
        for (int hf = 0; hf < 2; ++hf)
            c[mt][hf] = (f32x4){0.f, 0.f, 0.f, 0.f};

    const bf16x8* __restrict__ wfrag = (const bf16x8*)whext;
    const bf16x8* __restrict__ dfrag = (const bf16x8*)wdp;

    for (int step = 0; step < STEPS; ++step) {
        __syncthreads();   // hext (h + x_t slot) ready

        f32x4 acc[4][8];   // [m-tile][ntl: gate*2+half]
#pragma unroll
        for (int mt = 0; mt < 4; ++mt)
#pragma unroll
            for (int ntl = 0; ntl < 8; ++ntl) {
                float bv = bias[ntl];
                acc[mt][ntl] = (f32x4){bv, bv, bv, bv};
            }

#pragma unroll
        for (int kt = 0; kt < 9; ++kt) {
            bf16x8 af[4];
#pragma unroll
            for (int mt = 0; mt < 4; ++mt)
                af[mt] = *(const bf16x8*)&hbuf[(16 * mt + col) * PITCH + kt * 32 + quad * 8];
            bf16x8 bf_[8];
#pragma unroll
            for (int ntl = 0; ntl < 8; ++ntl)
                bf_[ntl] = wfrag[kt * 4096 + nb[ntl]];
#pragma unroll
            for (int mt = 0; mt < 4; ++mt)
#pragma unroll
                for (int ntl = 0; ntl < 8; ++ntl)
                    acc[mt][ntl] = __builtin_amdgcn_mfma_f32_16x16x32_bf16(
                        af[mt], bf_[ntl], acc[mt][ntl], 0, 0, 0);
        }

        __syncthreads();   // all hext reads done; safe to overwrite h and x_t

        // gates + state update; C/D layout: col = lane&15, row = quad*4 + r
#pragma unroll
        for (int mt = 0; mt < 4; ++mt)
#pragma unroll
            for (int hf = 0; hf < 2; ++hf) {
                f32x4 zi = acc[mt][0 + hf];
                f32x4 zf = acc[mt][2 + hf];
                f32x4 zg = acc[mt][4 + hf];
                f32x4 zo = acc[mt][6 + hf];
#pragma unroll
                for (int r = 0; r < 4; ++r) {
                    float iv = sigm(zi[r]);
                    float fv = sigm(zf[r]);
                    float gv = tanh_f(zg[r]);
                    float ov = sigm(zo[r]);
                    float cn = fv * c[mt][hf][r] + iv * gv;
                    c[mt][hf][r] = cn;
                    float hn = ov * tanh_f(cn);
                    int m = 16 * mt + 4 * quad + r;
                    int u = 32 * w + 16 * hf + col;
                    hbuf[m * PITCH + u] = f2bf(hn);
                }
            }

        if (step < WARM - 1) {
            if (w == 0) {   // prefetch next warmup x_t
                const float4 xv = *(const float4*)(x + (rowBase + l) * 192 + (step + 1) * 4);
                u16* p = &hbuf[l * PITCH + 256];
                p[0] = f2bf(xv.x); p[1] = f2bf(xv.y); p[2] = f2bf(xv.z); p[3] = f2bf(xv.w);
            }
        } else {
            __syncthreads();   // h_new visible for pred GEMM
            if (w < 4) {       // pred = h @ Wd + bd ; wave w -> m-tile w
                const int mt = w;
                f32x4 pacc = (f32x4){0.f, 0.f, 0.f, 0.f};
#pragma unroll
                for (int kt = 0; kt < 8; ++kt) {   // K=256 (h only)
                    bf16x8 af = *(const bf16x8*)&hbuf[(16 * mt + col) * PITCH + kt * 32 + quad * 8];
                    bf16x8 bf_ = dfrag[kt * 64 + l];
                    pacc = __builtin_amdgcn_mfma_f32_16x16x32_bf16(af, bf_, pacc, 0, 0, 0);
                }
                if (col < 4) {
                    int s = step - (WARM - 1);
#pragma unroll
                    for (int r = 0; r < 4; ++r) {
                        int m = 16 * mt + 4 * quad + r;
                        float pv = pacc[r] + bdv;
                        out[((rowBase + m) * 24 + s) * 4 + col] = pv;
                        hbuf[m * PITCH + 256 + col] = f2bf(pv);   // feed back as x_t
                    }
                }
            }
        }
    }
}

extern "C" void kernel_launch(void* const* d_in, const int* in_sizes, int n_in,
                              void* d_out, int out_size, void* d_ws, size_t ws_size,
                              hipStream_t stream) {
    const float* x  = (const float*)d_in[0];   // [16384,48,4]
    const float* Wx = (const float*)d_in[1];   // [4,1024]
    const float* Wh = (const float*)d_in[2];   // [256,1024]
    const float* b  = (const float*)d_in[3];   // [1024]
    const float* Wd = (const float*)d_in[4];   // [256,4]
    const float* bd = (const float*)d_in[5];   // [4]
    float* out = (float*)d_out;                // [16384,24,4] fp32

    u16* whext = (u16*)d_ws;                        // 589824 B
    u16* wdp = (u16*)((char*)d_ws + 36864 * 16);    // 8192 B

    prep_weights<<<(36864 + 512 + 255) / 256, 256, 0, stream>>>(Wx, Wh, Wd, whext, wdp);
    lstm_main<<<256, 512, 0, stream>>>(x, b, bd, whext, wdp, out);
}

// Round 2
// 2041.814 us; speedup vs baseline: 1.1057x; 1.1057x over previous
//
#include <hip/hip_runtime.h>

// LSTM feedback net: B=16384, T=48 warmup, F=4, UNITS=256, 24 AR steps.
// R2: 16 waves/block, 4 n-tiles (one per gate) per wave -> acc 64 regs/wave
// (was 128), 4 waves/SIMD TLP (was 2). Bias folded into GEMM via K-row 260
// (hext[.][260] = 1.0). Eliminates the R1 scratch spill (1.2 GB writes) that
// thrashed L2 and pushed the weight stream to HBM.

typedef unsigned short u16;
typedef __attribute__((ext_vector_type(8))) short bf16x8;
typedef __attribute__((ext_vector_type(4))) float f32x4;

#define PITCH 296   // hext row pitch in elems (288+8; 592 B = 16B-aligned, 2-way-bank only)
#define WARM 48
#define STEPS 71    // 48 warmup + 23 AR cell steps

__device__ __forceinline__ u16 f2bf(float f) {
    unsigned u = __float_as_uint(f);
    u += 0x7FFFu + ((u >> 16) & 1u);   // round-to-nearest-even
    return (u16)(u >> 16);
}

__device__ __forceinline__ float sigm(float x) {
    return __builtin_amdgcn_rcpf(1.0f + __expf(-x));
}
// tanh(x) = 2*sigmoid(2x)-1 ; saturates correctly without NaN
__device__ __forceinline__ float tanh_f(float x) {
    return __builtin_amdgcn_rcpf(1.0f + __expf(-2.0f * x)) * 2.0f - 1.0f;
}

// ---- prep: pack Whext (K=288 x N=1024) and Wdext (K=288 x N=16) into bf16
// MFMA B-fragment blocks: block (kt, nt) = 64 lanes x 16B, lane l holds
// B[k0 + (l>>4)*8 + j][nt*16 + (l&15)], j=0..7.
// K rows: 0..255 = Wh (or Wd), 256..259 = Wx (or 0), 260 = b (or bd), else 0.
__global__ void prep_weights(const float* __restrict__ Wx,
                             const float* __restrict__ Wh,
                             const float* __restrict__ b,
                             const float* __restrict__ Wd,
                             const float* __restrict__ bd,
                             u16* __restrict__ whext,
                             u16* __restrict__ wdp) {
    int idx = blockIdx.x * 256 + threadIdx.x;   // one thread per 16B chunk
    if (idx < 36864) {                          // 9 kt * 64 nt * 64 lanes
        int lane = idx & 63;
        int blk = idx >> 6;
        int nt = blk & 63;
        int kt = blk >> 6;
        int kbase = kt * 32 + (lane >> 4) * 8;
        int n = nt * 16 + (lane & 15);
        u16 v[8];
#pragma unroll
        for (int j = 0; j < 8; ++j) {
            int k = kbase + j;
            float f = 0.0f;
            if (k < 256) f = Wh[k * 1024 + n];
            else if (k < 260) f = Wx[(k - 256) * 1024 + n];
            else if (k == 260) f = b[n];
            v[j] = f2bf(f);
        }
        ushort4* dst = (ushort4*)(whext + (size_t)idx * 8);
        dst[0] = make_ushort4(v[0], v[1], v[2], v[3]);
        dst[1] = make_ushort4(v[4], v[5], v[6], v[7]);
    } else if (idx < 36864 + 576) {             // Wdext: 9 kt * 64 lanes, N-tile 0
        int id2 = idx - 36864;
        int lane = id2 & 63;
        int kt = id2 >> 6;
        int kbase = kt * 32 + (lane >> 4) * 8;
        int n = lane & 15;
        u16 v[8];
#pragma unroll
        for (int j = 0; j < 8; ++j) {
            int k = kbase + j;
            float f = 0.0f;
            if (n < 4) {
                if (k < 256) f = Wd[k * 4 + n];
                else if (k == 260) f = bd[n];
            }
            v[j] = f2bf(f);
        }
        ushort4* dst = (ushort4*)(wdp + (size_t)id2 * 8);
        dst[0] = make_ushort4(v[0], v[1], v[2], v[3]);
        dst[1] = make_ushort4(v[4], v[5], v[6], v[7]);
    }
}

__global__ __launch_bounds__(1024, 4) void lstm_main(
    const float* __restrict__ x, const u16* __restrict__ whext,
    const u16* __restrict__ wdp, float* __restrict__ out) {
    __shared__ u16 hbuf[64 * PITCH];   // hext: [row 0..63][k 0..287], bf16

    const int tid = threadIdx.x;
    const int w = tid >> 6;        // wave 0..15
    const int l = tid & 63;
    const int col = l & 15;
    const int quad = l >> 4;
    const long long rowBase = (long long)blockIdx.x * 64;

    for (int i = tid; i < 64 * PITCH; i += 1024) hbuf[i] = 0;
    __syncthreads();   // zero-fill complete before specials

    if (tid < 64) {
        // constant-1 column feeding the bias row of Whext/Wdext
        hbuf[tid * PITCH + 260] = (u16)0x3F80;   // bf16(1.0)
        // x_t for step 0 -> hext[m][256:260]
        const float4 xv = *(const float4*)(x + (rowBase + tid) * 192);
        u16* p = &hbuf[tid * PITCH + 256];
        p[0] = f2bf(xv.x); p[1] = f2bf(xv.y); p[2] = f2bf(xv.z); p[3] = f2bf(xv.w);
    }

    f32x4 c[4];        // cell state: unit = 16w+col, row m = 16mt+4quad+r
#pragma unroll
    for (int mt = 0; mt < 4; ++mt) c[mt] = (f32x4){0.f, 0.f, 0.f, 0.f};

    const bf16x8* __restrict__ wfrag = (const bf16x8*)whext;
    const bf16x8* __restrict__ dfrag = (const bf16x8*)wdp;
    const int base = w * 64 + l;   // fragment index within a (kt, gate) block

    for (int step = 0; step < STEPS; ++step) {
        __syncthreads();   // hext (h + x_t + bias-1 cols) ready

        f32x4 acc[4][4];   // [m-tile][gate]
#pragma unroll
        for (int mt = 0; mt < 4; ++mt)
#pragma unroll
            for (int g = 0; g < 4; ++g) acc[mt][g] = (f32x4){0.f, 0.f, 0.f, 0.f};

#pragma unroll
        for (int kt = 0; kt < 9; ++kt) {
            bf16x8 af[4];
#pragma unroll
            for (int mt = 0; mt < 4; ++mt)
                af[mt] = *(const bf16x8*)&hbuf[(16 * mt + col) * PITCH + kt * 32 + quad * 8];
            bf16x8 bfr[4];
#pragma unroll
            for (int g = 0; g < 4; ++g)
                bfr[g] = wfrag[kt * 4096 + g * 1024 + base];   // ntile = 16g + w
#pragma unroll
            for (int g = 0; g < 4; ++g)
#pragma unroll
                for (int mt = 0; mt < 4; ++mt)
                    acc[mt][g] = __builtin_amdgcn_mfma_f32_16x16x32_bf16(
                        af[mt], bfr[g], acc[mt][g], 0, 0, 0);
        }

        __syncthreads();   // all hext reads done; safe to overwrite h and x_t

        // gates + state update; C/D layout: col = lane&15, row = quad*4 + r
#pragma unroll
        for (int mt = 0; mt < 4; ++mt) {
#pragma unroll
            for (int r = 0; r < 4; ++r) {
                float iv = sigm(acc[mt][0][r]);
                float fv = sigm(acc[mt][1][r]);
                float gv = tanh_f(acc[mt][2][r]);
                float ov = sigm(acc[mt][3][r]);
                float cn = fv * c[mt][r] + iv * gv;
                c[mt][r] = cn;
                float hn = ov * tanh_f(cn);
                int m = 16 * mt + 4 * quad + r;
                hbuf[m * PITCH + 16 * w + col] = f2bf(hn);
            }
        }

        if (step < WARM - 1) {
            if (w == 0) {   // prefetch next warmup x_t (cols 256..259 only)
                const float4 xv = *(const float4*)(x + (rowBase + l) * 192 + (step + 1) * 4);
                u16* p = &hbuf[l * PITCH + 256];
                p[0] = f2bf(xv.x); p[1] = f2bf(xv.y); p[2] = f2bf(xv.z); p[3] = f2bf(xv.w);
            }
        } else {
            __syncthreads();   // h_new visible for pred GEMM
            if (w < 4) {       // pred = h @ Wdext (bd via bias row); wave w -> m-tile w
                f32x4 pacc = (f32x4){0.f, 0.f, 0.f, 0.f};
#pragma unroll
                for (int kt = 0; kt < 9; ++kt) {
                    bf16x8 af = *(const bf16x8*)&hbuf[(16 * w + col) * PITCH + kt * 32 + quad * 8];
                    bf16x8 bfr = dfrag[kt * 64 + l];
                    pacc = __builtin_amdgcn_mfma_f32_16x16x32_bf16(af, bfr, pacc, 0, 0, 0);
                }
                if (col < 4) {
                    int s = step - (WARM - 1);
#pragma unroll
                    for (int r = 0; r < 4; ++r) {
                        int m = 16 * w + 4 * quad + r;
                        float pv = pacc[r];
                        out[((rowBase + m) * 24 + s) * 4 + col] = pv;
                        hbuf[m * PITCH + 256 + col] = f2bf(pv);   // feed back as x_t
                    }
                }
            }
        }
    }
}

extern "C" void kernel_launch(void* const* d_in, const int* in_sizes, int n_in,
                              void* d_out, int out_size, void* d_ws, size_t ws_size,
                              hipStream_t stream) {
    const float* x  = (const float*)d_in[0];   // [16384,48,4]
    const float* Wx = (const float*)d_in[1];   // [4,1024]
    const float* Wh = (const float*)d_in[2];   // [256,1024]
    const float* b  = (const float*)d_in[3];   // [1024]
    const float* Wd = (const float*)d_in[4];   // [256,4]
    const float* bd = (const float*)d_in[5];   // [4]
    float* out = (float*)d_out;                // [16384,24,4] fp32

    u16* whext = (u16*)d_ws;                        // 589824 B
    u16* wdp = (u16*)((char*)d_ws + 36864 * 16);    // 9216 B

    prep_weights<<<(36864 + 576 + 255) / 256, 256, 0, stream>>>(Wx, Wh, b, Wd, bd, whext, wdp);
    lstm_main<<<256, 1024, 0, stream>>>(x, whext, wdp, out);
}

// Round 3
// 1423.601 us; speedup vs baseline: 1.5859x; 1.4343x over previous
//
#include <hip/hip_runtime.h>

// LSTM feedback net: B=16384, T=48 warmup, F=4, UNITS=256, 24 AR steps.
// R3: fit the 128-reg/wave cap (1024-thr block forces 4 waves/SIMD).
//  - c state moved to LDS (-16 persistent regs; touched once/step).
//  - GEMM transposed: z^T = Whext^T @ hext^T. Same packed weight buffer fed
//    as operand A (A/B fragment layouts are mutual transposes), same LDS
//    h-reads fed as operand B. Gate outputs land unit-major per lane ->
//    h-writes are ds_write_b64 x4 (was ds_write_u16 x16), pred store is one
//    float4, weight fragments stream per-gate (8 live regs, was 16).
//  - hbuf double-buffered: 1 barrier per warmup step (was 2).
// Est. regs: acc 64 (AGPR) + hb 16 + wa 8 + addr/temps ~20 = ~108 < 128.

typedef unsigned short u16;
typedef __attribute__((ext_vector_type(8))) short bf16x8;
typedef __attribute__((ext_vector_type(4))) float f32x4;

#define PITCH 296    // hext row pitch, elems (592 B/row, 16B-aligned)
#define HB 18944     // elems per h buffer (64*296)
#define CPITCH 264   // c row pitch, floats (1056 B, 16B-aligned)
#define WARM 48
#define STEPS 71     // 48 warmup + 23 AR cell steps

__device__ __forceinline__ u16 f2bf(float f) {
    unsigned u = __float_as_uint(f);
    u += 0x7FFFu + ((u >> 16) & 1u);   // round-to-nearest-even
    return (u16)(u >> 16);
}

__device__ __forceinline__ float sigm(float x) {
    return __builtin_amdgcn_rcpf(1.0f + __expf(-x));
}
// tanh(x) = 2*sigmoid(2x)-1 ; saturates correctly without NaN
__device__ __forceinline__ float tanh_f(float x) {
    return __builtin_amdgcn_rcpf(1.0f + __expf(-2.0f * x)) * 2.0f - 1.0f;
}

// ---- prep (UNCHANGED from R2): pack Whext (K=288 x N=1024) and Wdext into
// fragment blocks; lane l of block (kt,nt) holds W[kt*32+(l>>4)*8+j][nt*16+(l&15)].
// Used as operand A in the main kernel: A[m=l&15][k=quad*8+j] = W^T fragment.
// K rows: 0..255 = Wh (or Wd), 256..259 = Wx (or 0), 260 = b (or bd), else 0.
__global__ void prep_weights(const float* __restrict__ Wx,
                             const float* __restrict__ Wh,
                             const float* __restrict__ b,
                             const float* __restrict__ Wd,
                             const float* __restrict__ bd,
                             u16* __restrict__ whext,
                             u16* __restrict__ wdp) {
    int idx = blockIdx.x * 256 + threadIdx.x;   // one thread per 16B chunk
    if (idx < 36864) {                          // 9 kt * 64 nt * 64 lanes
        int lane = idx & 63;
        int blk = idx >> 6;
        int nt = blk & 63;
        int kt = blk >> 6;
        int kbase = kt * 32 + (lane >> 4) * 8;
        int n = nt * 16 + (lane & 15);
        u16 v[8];
#pragma unroll
        for (int j = 0; j < 8; ++j) {
            int k = kbase + j;
            float f = 0.0f;
            if (k < 256) f = Wh[k * 1024 + n];
            else if (k < 260) f = Wx[(k - 256) * 1024 + n];
            else if (k == 260) f = b[n];
            v[j] = f2bf(f);
        }
        ushort4* dst = (ushort4*)(whext + (size_t)idx * 8);
        dst[0] = make_ushort4(v[0], v[1], v[2], v[3]);
        dst[1] = make_ushort4(v[4], v[5], v[6], v[7]);
    } else if (idx < 36864 + 576) {             // Wdext: 9 kt * 64 lanes
        int id2 = idx - 36864;
        int lane = id2 & 63;
        int kt = id2 >> 6;
        int kbase = kt * 32 + (lane >> 4) * 8;
        int n = lane & 15;
        u16 v[8];
#pragma unroll
        for (int j = 0; j < 8; ++j) {
            int k = kbase + j;
            float f = 0.0f;
            if (n < 4) {
                if (k < 256) f = Wd[k * 4 + n];
                else if (k == 260) f = bd[n];
            }
            v[j] = f2bf(f);
        }
        ushort4* dst = (ushort4*)(wdp + (size_t)id2 * 8);
        dst[0] = make_ushort4(v[0], v[1], v[2], v[3]);
        dst[1] = make_ushort4(v[4], v[5], v[6], v[7]);
    }
}

__global__ __launch_bounds__(1024, 4) void lstm_main(
    const float* __restrict__ x, const u16* __restrict__ whext,
    const u16* __restrict__ wdp, float* __restrict__ out) {
    __shared__ __align__(16) unsigned char smem[143360];
    u16* hbuf = (u16*)smem;                    // 2 buffers x 18944 elems (bf16)
    float* cbuf = (float*)(smem + 75776);      // c: [batch 64][unit, pitch 264] fp32

    const int tid = threadIdx.x;
    const int w = tid >> 6;        // wave 0..15 -> units [16w, 16w+16)
    const int l = tid & 63;
    const int col = l & 15;        // batch col within tile
    const int quad = l >> 4;
    const long long rowBase = (long long)blockIdx.x * 64;

    {   // zero LDS: h buffers (incl. K-pad cols 261..287) + c
        int4 z = make_int4(0, 0, 0, 0);
        for (int i = tid; i < 8960; i += 1024) ((int4*)smem)[i] = z;
    }
    __syncthreads();
    if (tid < 64) {
        // constant-1 column (k=260) feeding the bias row, in BOTH buffers
        hbuf[tid * PITCH + 260] = (u16)0x3F80;
        hbuf[HB + tid * PITCH + 260] = (u16)0x3F80;
        // x_0 -> buffer 0, cols 256..259
        const float4 xv = *(const float4*)(x + (rowBase + tid) * 192);
        u16* p = &hbuf[tid * PITCH + 256];
        p[0] = f2bf(xv.x); p[1] = f2bf(xv.y); p[2] = f2bf(xv.z); p[3] = f2bf(xv.w);
    }

    const bf16x8* __restrict__ wfrag = (const bf16x8*)whext;
    const bf16x8* __restrict__ dfrag = (const bf16x8*)wdp;

    for (int step = 0; step < STEPS; ++step) {
        const u16* hr = hbuf + (step & 1) * HB;      // read buffer
        u16* hw = hbuf + ((step & 1) ^ 1) * HB;      // write buffer
        __syncthreads();   // h/x/bias of hr ready; all prior reads of hw done

        f32x4 acc[4][4];   // [batch-tile][gate]; D = z^T tile
#pragma unroll
        for (int bt = 0; bt < 4; ++bt)
#pragma unroll
            for (int g = 0; g < 4; ++g) acc[bt][g] = (f32x4){0.f, 0.f, 0.f, 0.f};

#pragma unroll
        for (int kt = 0; kt < 9; ++kt) {
            bf16x8 hb[4];   // B operand: hext[16bt+col][k] (k-contig per lane)
#pragma unroll
            for (int bt = 0; bt < 4; ++bt)
                hb[bt] = *(const bf16x8*)&hr[(16 * bt + col) * PITCH + kt * 32 + quad * 8];
#pragma unroll
            for (int g = 0; g < 4; ++g) {
                bf16x8 wa = wfrag[kt * 4096 + (16 * g + w) * 64 + l];  // A: W^T M-tile 16g+w
#pragma unroll
                for (int bt = 0; bt < 4; ++bt)
                    acc[bt][g] = __builtin_amdgcn_mfma_f32_16x16x32_bf16(
                        wa, hb[bt], acc[bt][g], 0, 0, 0);
            }
        }

        // gates; lane holds units u = 16w + 4quad + r, batch m = 16bt + col
#pragma unroll
        for (int bt = 0; bt < 4; ++bt) {
            float* cp = &cbuf[(16 * bt + col) * CPITCH + 16 * w + 4 * quad];
            f32x4 cold = *(const f32x4*)cp;
            f32x4 cnew;
            u16 hh[4];
#pragma unroll
            for (int r = 0; r < 4; ++r) {
                float iv = sigm(acc[bt][0][r]);
                float fv = sigm(acc[bt][1][r]);
                float gv = tanh_f(acc[bt][2][r]);
                float ov = sigm(acc[bt][3][r]);
                float cn = fv * cold[r] + iv * gv;
                cnew[r] = cn;
                hh[r] = f2bf(ov * tanh_f(cn));
            }
            *(f32x4*)cp = cnew;
            *(ushort4*)&hw[(16 * bt + col) * PITCH + 16 * w + 4 * quad] =
                make_ushort4(hh[0], hh[1], hh[2], hh[3]);
        }

        if (step < WARM - 1) {
            if (w == 0) {   // x_{step+1} -> write buffer (read next step)
                const float4 xv = *(const float4*)(x + (rowBase + l) * 192 + (step + 1) * 4);
                u16* p = &hw[l * PITCH + 256];
                p[0] = f2bf(xv.x); p[1] = f2bf(xv.y); p[2] = f2bf(xv.z); p[3] = f2bf(xv.w);
            }
        } else {
            __syncthreads();   // h_new in hw visible for pred GEMM
            if (w < 4) {       // pred^T = Wdext^T @ h_new^T ; wave w -> batch-tile w
                f32x4 pacc = (f32x4){0.f, 0.f, 0.f, 0.f};
#pragma unroll
                for (int kt = 0; kt < 9; ++kt) {
                    bf16x8 hb = *(const bf16x8*)&hw[(16 * w + col) * PITCH + kt * 32 + quad * 8];
                    bf16x8 wa = dfrag[kt * 64 + l];
                    pacc = __builtin_amdgcn_mfma_f32_16x16x32_bf16(wa, hb, pacc, 0, 0, 0);
                }
                if (quad == 0) {   // rows 0..3 = F; lane holds all 4 F for batch 16w+col
                    int s = step - (WARM - 1);
                    *(float4*)&out[((rowBase + 16 * w + col) * 24 + s) * 4] =
                        make_float4(pacc[0], pacc[1], pacc[2], pacc[3]);
                    // feed back as next x_t
                    *(ushort4*)&hw[(16 * w + col) * PITCH + 256] =
                        make_ushort4(f2bf(pacc[0]), f2bf(pacc[1]), f2bf(pacc[2]), f2bf(pacc[3]));
                }
            }
        }
    }
}

extern "C" void kernel_launch(void* const* d_in, const int* in_sizes, int n_in,
                              void* d_out, int out_size, void* d_ws, size_t ws_size,
                              hipStream_t stream) {
    const float* x  = (const float*)d_in[0];   // [16384,48,4]
    const float* Wx = (const float*)d_in[1];   // [4,1024]
    const float* Wh = (const float*)d_in[2];   // [256,1024]
    const float* b  = (const float*)d_in[3];   // [1024]
    const float* Wd = (const float*)d_in[4];   // [256,4]
    const float* bd = (const float*)d_in[5];   // [4]
    float* out = (float*)d_out;                // [16384,24,4] fp32

    u16* whext = (u16*)d_ws;                        // 589824 B
    u16* wdp = (u16*)((char*)d_ws + 36864 * 16);    // 9216 B

    prep_weights<<<(36864 + 576 + 255) / 256, 256, 0, stream>>>(Wx, Wh, b, Wd, bd, whext, wdp);
    lstm_main<<<256, 1024, 0, stream>>>(x, whext, wdp, out);
}